// Round 1
// baseline (220.377 us; speedup 1.0000x reference)
//
#include <hip/hip_runtime.h>

// Wavelet low-pass analysis (stride-2) + synthesis (transposed conv) fused
// into two 18-tap polyphase FIR filters applied directly to the input.
//
//   even p: ya[p] = sum_d We[d] * sig_m[p + d - 8]
//   odd  p: ya[p] = sum_d Wo[d] * sig_m[p + d - 9]
// with We[d] = sum_j RL[8-2j]*RL[d-2j], Wo[d] = sum_j RL[9-2j]*RL[d-2j]
// (valid terms only), sig_m = symmetric extension of the 524288-long
// flattened per-batch signal.

#define L_SIG 524288
#define TILE 1024
#define SMEM_N (TILE + 32)   // tile + 16 halo each side (only +-9 needed; 16 keeps float4 alignment)

constexpr float RL[10] = {
    0.160102397974125f,   0.6038292697974729f,  0.7243085284385744f,
    0.13842814590110342f, -0.24229488706619015f, -0.03224486958502952f,
    0.07757149384006515f, -0.006241490213011705f, -0.012580751999015526f,
    0.003335725285001549f};

struct Coef { float we[18]; float wo[18]; };

constexpr Coef make_coef() {
    Coef c{};
    for (int d = 0; d < 18; ++d) {
        float se = 0.f, so = 0.f;
        for (int j = 0; j < 5; ++j) {
            int i = d - 2 * j;               // REC_LO tap index
            if (i >= 0 && i < 10) {
                se += RL[8 - 2 * j] * RL[i]; // DEC_LO[2j+1] = RL[8-2j]
                so += RL[9 - 2 * j] * RL[i]; // DEC_LO[2j]   = RL[9-2j]
            }
        }
        c.we[d] = se;
        c.wo[d] = so;
    }
    return c;
}

constexpr Coef CF = make_coef();

__global__ __launch_bounds__(256)
void wavelet_fused_kernel(const float* __restrict__ x, float* __restrict__ out) {
    __shared__ float s[SMEM_N];

    const int batch = blockIdx.y;
    const int p0    = blockIdx.x * TILE;
    const float* xb = x   + (size_t)batch * L_SIG;
    float*       ob = out + (size_t)batch * L_SIG;

    const bool edge = (blockIdx.x == 0) || (blockIdx.x == gridDim.x - 1);

    if (edge) {
        // Scalar loads with symmetric-mirror index mapping (2 blocks / batch).
        for (int t = threadIdx.x; t < SMEM_N; t += 256) {
            int k  = p0 - 16 + t;
            int km = (k < 0) ? (-1 - k) : ((k >= L_SIG) ? (2 * L_SIG - 1 - k) : k);
            s[t] = xb[km];
        }
    } else {
        // Fast path: fully interior, aligned float4 loads. 264 float4 = 1056 floats.
        const float4* src = (const float4*)(xb + p0 - 16);
        float4* s4 = (float4*)s;
        int t = threadIdx.x;
        s4[t] = src[t];
        if (t < 8) s4[256 + t] = src[256 + t];
    }
    __syncthreads();

    // Each thread: 4 consecutive outputs p0+q .. p0+q+3 (even,odd,even,odd).
    const int q = threadIdx.x * 4;

    float v[20];
#pragma unroll
    for (int r = 0; r < 5; ++r) {
        float4 f = ((const float4*)(s + q + 8))[r];
        v[4 * r + 0] = f.x;
        v[4 * r + 1] = f.y;
        v[4 * r + 2] = f.z;
        v[4 * r + 3] = f.w;
    }

    float o0 = 0.f, o1 = 0.f, o2 = 0.f, o3 = 0.f;
#pragma unroll
    for (int d = 0; d < 18; ++d) {
        o0 += CF.we[d] * v[d];       // even output at q     : s[q+8+d]
        o1 += CF.wo[d] * v[d];       // odd  output at q+1   : s[(q+1)+7+d]
        o2 += CF.we[d] * v[d + 2];   // even output at q+2
        o3 += CF.wo[d] * v[d + 2];   // odd  output at q+3
    }

    float4 o = make_float4(o0, o1, o2, o3);
    *((float4*)(ob + p0 + q)) = o;
}

extern "C" void kernel_launch(void* const* d_in, const int* in_sizes, int n_in,
                              void* d_out, int out_size, void* d_ws, size_t ws_size,
                              hipStream_t stream) {
    const float* x = (const float*)d_in[0];
    float* out     = (float*)d_out;

    const int B = in_sizes[0] / L_SIG;            // 64
    dim3 grid(L_SIG / TILE, B);                   // (512, 64)
    wavelet_fused_kernel<<<grid, 256, 0, stream>>>(x, out);
}